// Round 3
// baseline (355.138 us; speedup 1.0000x reference)
//
#include <hip/hip_runtime.h>

#define T_ 32
#define S_ 4096
#define F_ 256
#define A_ 64
#define G_ 16            // objects per block
#define NBLK (S_ / G_)   // 256 blocks = 1 per CU

typedef __attribute__((ext_vector_type(8))) short s8v;   // 8 x bf16 (MFMA A/B frag)
typedef __attribute__((ext_vector_type(4))) float f4v;   // 4 x f32  (MFMA C/D frag)
typedef __attribute__((ext_vector_type(4))) short s4v;   // 8-byte packed store

#define MFMA(a, b, c) __builtin_amdgcn_mfma_f32_16x16x32_bf16((a), (b), (c), 0, 0, 0)

__device__ __forceinline__ unsigned short f2bf(float f) {
    unsigned int u = __builtin_bit_cast(unsigned int, f);
    u += 0x7FFFu + ((u >> 16) & 1u);   // round-to-nearest-even
    return (unsigned short)(u >> 16);
}

__device__ __forceinline__ s8v cvt8(float4 a, float4 b) {
    s8v p;
    p[0] = (short)f2bf(a.x); p[1] = (short)f2bf(a.y);
    p[2] = (short)f2bf(a.z); p[3] = (short)f2bf(a.w);
    p[4] = (short)f2bf(b.x); p[5] = (short)f2bf(b.y);
    p[6] = (short)f2bf(b.z); p[7] = (short)f2bf(b.w);
    return p;
}

// ---- pre-pass: convert Wa[64x256], Wb[64x256], Wg[256x256] f32 -> bf16 in d_ws ----
__global__ void convert_weights(const float* __restrict__ Wa,
                                const float* __restrict__ Wb,
                                const float* __restrict__ Wg,
                                unsigned short* __restrict__ wsB)
{
    int base = (blockIdx.x * 256 + threadIdx.x) * 4;
    const float* src;
    if (base < 16384)      src = Wa + base;
    else if (base < 32768) src = Wb + (base - 16384);
    else                   src = Wg + (base - 32768);
    float4 v = *(const float4*)src;
    s4v p;
    p[0] = (short)f2bf(v.x); p[1] = (short)f2bf(v.y);
    p[2] = (short)f2bf(v.z); p[3] = (short)f2bf(v.w);
    *(s4v*)(wsB + base) = p;
}

// LDS layout (bytes)
#define XROW 1040                    // 1024 + 16 pad: breaks bank alias (4t mod 32 shift)
#define XS_OFF 0                     // X f32 [2][32][XROW]  = 66560
#define FT_OFF 66560                 // featsT bf16 [2][256][64] = 32768 (chunk-swizzled)
#define TH_OFF 99328                 // theta [32][128B] = 4096
#define PH_OFF 103424                // phi   [32][128B] = 4096
#define AT_OFF 107520                // attn  [32][64B]  = 2048
#define LDS_BYTES 109568

__global__ __launch_bounds__(256, 1) void fused_temporal(
    const float* __restrict__ X,
    const unsigned short* __restrict__ wsB,
    const float* __restrict__ ba, const float* __restrict__ bb,
    const float* __restrict__ bg,
    float* __restrict__ out)
{
    __shared__ alignas(16) unsigned char smem[LDS_BYTES];
    const int tid  = threadIdx.x;
    const int wave = tid >> 6;
    const int lane = tid & 63;
    const int quad = lane >> 4;
    const int l15  = lane & 15;
    const int s0   = blockIdx.x * G_;

    // ---- hoist weights: wave w's B-fragments, resident in VGPRs for the whole kernel ----
    s8v waF[8], wbF[8], wgF[4][8];
    {
        const unsigned short* wa_row = wsB         + (size_t)(16 * wave + l15) * F_ + quad * 8;
        const unsigned short* wb_row = wsB + 16384 + (size_t)(16 * wave + l15) * F_ + quad * 8;
        #pragma unroll
        for (int ks = 0; ks < 8; ++ks) {
            waF[ks] = *(const s8v*)(wa_row + ks * 32);
            wbF[ks] = *(const s8v*)(wb_row + ks * 32);
        }
        #pragma unroll
        for (int g = 0; g < 4; ++g) {
            const unsigned short* wg_row = wsB + 32768 + (size_t)(64 * wave + 16 * g + l15) * F_ + quad * 8;
            #pragma unroll
            for (int ks = 0; ks < 8; ++ks) wgF[g][ks] = *(const s8v*)(wg_row + ks * 32);
        }
    }
    const float biasa = ba[16 * wave + l15];
    const float biasb = bb[16 * wave + l15];
    float biasg[4];
    #pragma unroll
    for (int g = 0; g < 4; ++g) biasg[g] = bg[64 * wave + 16 * g + l15];

    // ---- prologue: stage X[s0] f32 into buf 0 (each wave: 8 rows of 1 KB, lane*16B) ----
    #pragma unroll
    for (int r = 0; r < 8; ++r) {
        int t = wave * 8 + r;
        float4 v = *(const float4*)(X + ((size_t)(t * S_ + s0)) * F_ + lane * 4);
        *(float4*)(&smem[XS_OFF + t * XROW + lane * 16]) = v;
    }
    __syncthreads();

    for (int i = 0; i < G_; ++i) {
        const int p = i & 1;
        const int s = s0 + i;
        const int xb  = XS_OFF + p * (32 * XROW);
        const int xbn = XS_OFF + (1 - p) * (32 * XROW);
        const int ftb = FT_OFF + p * 16384;

        // prefetch next object's X rows into registers (consumed before barrier A)
        float4 pf[8];
        if (i + 1 < G_) {
            #pragma unroll
            for (int r = 0; r < 8; ++r) {
                int t = wave * 8 + r;
                pf[r] = *(const float4*)(X + ((size_t)(t * S_ + s + 1)) * F_ + lane * 4);
            }
        }

        // ---- phase 1 (fused 1a+1b), ks-outer; all accumulators live ----
        f4v ta0 = {0,0,0,0}, ta1 = {0,0,0,0}, pa0 = {0,0,0,0}, pa1 = {0,0,0,0};
        f4v fa[4][2];
        #pragma unroll
        for (int g = 0; g < 4; ++g) { fa[g][0] = (f4v){0,0,0,0}; fa[g][1] = (f4v){0,0,0,0}; }

        #pragma unroll
        for (int ks = 0; ks < 8; ++ks) {
            s8v a0, a1;
            {
                const unsigned char* b0 = &smem[xb + l15 * XROW + ks * 128 + quad * 32];
                a0 = cvt8(*(const float4*)(b0), *(const float4*)(b0 + 16));
                const unsigned char* b1 = &smem[xb + (l15 + 16) * XROW + ks * 128 + quad * 32];
                a1 = cvt8(*(const float4*)(b1), *(const float4*)(b1 + 16));
            }
            ta0 = MFMA(a0, waF[ks], ta0);
            ta1 = MFMA(a1, waF[ks], ta1);
            pa0 = MFMA(a0, wbF[ks], pa0);
            pa1 = MFMA(a1, wbF[ks], pa1);
            #pragma unroll
            for (int g = 0; g < 4; ++g) {
                fa[g][0] = MFMA(a0, wgF[g][ks], fa[g][0]);
                fa[g][1] = MFMA(a1, wgF[g][ks], fa[g][1]);
            }
        }

        // 1a epilogue: theta/phi -> LDS (bf16, chunk-swizzled rows of 128 B)
        {
            int a_col = 16 * wave + l15;
            int chunk = a_col >> 3;
            int sub   = (a_col & 7) * 2;
            #pragma unroll
            for (int mt = 0; mt < 2; ++mt) {
                f4v va = mt ? ta1 : ta0;
                f4v vb = mt ? pa1 : pa0;
                #pragma unroll
                for (int r = 0; r < 4; ++r) {
                    int t  = quad * 4 + r + 16 * mt;
                    int sw = ((chunk + t) & 7) << 4;
                    *(unsigned short*)(&smem[TH_OFF + t * 128 + sw + sub]) = f2bf(va[r] + biasa);
                    *(unsigned short*)(&smem[PH_OFF + t * 128 + sw + sub]) = f2bf(vb[r] + biasb);
                }
            }
        }
        // 1b epilogue: featsT[f][u] -> LDS buf p (bf16, chunk-swizzled rows of 64 B)
        #pragma unroll
        for (int g = 0; g < 4; ++g) {
            int f = 64 * wave + 16 * g + l15;
            #pragma unroll
            for (int mt = 0; mt < 2; ++mt) {
                f4v v = fa[g][mt];
                int u0 = quad * 4 + 16 * mt;
                s4v pk;
                #pragma unroll
                for (int r = 0; r < 4; ++r) pk[r] = (short)f2bf(v[r] + biasg[g]);
                int addr = ftb + f * 64 + ((((u0 >> 3) + f) & 3) << 4) + (u0 & 7) * 2;
                *(s4v*)(&smem[addr]) = pk;
            }
        }

        // write prefetched X[i+1] into the other buffer (loads have had a full phase to land)
        if (i + 1 < G_) {
            #pragma unroll
            for (int r = 0; r < 8; ++r) {
                int t = wave * 8 + r;
                *(float4*)(&smem[xbn + t * XROW + lane * 16]) = pf[r];
            }
        }
        __syncthreads();   // barrier A: theta/phi/featsT ready; X[i+1] staged

        // ---- phase 2: attn = theta . phi^T ----
        {
            int mt = wave >> 1, nt = wave & 1;
            int t = l15 + 16 * mt;
            int u = l15 + 16 * nt;
            f4v acc = {0,0,0,0};
            #pragma unroll
            for (int ks = 0; ks < 2; ++ks) {
                int chunk = 4 * ks + quad;
                s8v av = *(const s8v*)(&smem[TH_OFF + t * 128 + (((chunk + t) & 7) << 4)]);
                s8v bv = *(const s8v*)(&smem[PH_OFF + u * 128 + (((chunk + u) & 7) << 4)]);
                acc = MFMA(av, bv, acc);
            }
            int chunk = u >> 3;
            int sub   = (u & 7) * 2;
            #pragma unroll
            for (int r = 0; r < 4; ++r) {
                int tt = quad * 4 + r + 16 * mt;
                *(unsigned short*)(&smem[AT_OFF + tt * 64 + (((chunk + tt) & 3) << 4) + sub]) = f2bf(acc[r]);
            }
        }
        __syncthreads();   // barrier B: attn ready

        // ---- phase 3: out = attn . feats ----
        {
            s8v aa[2];
            #pragma unroll
            for (int mt = 0; mt < 2; ++mt) {
                int t = l15 + 16 * mt;
                aa[mt] = *(const s8v*)(&smem[AT_OFF + t * 64 + (((quad + t) & 3) << 4)]);
            }
            #pragma unroll
            for (int g = 0; g < 4; ++g) {
                int f = 64 * wave + 16 * g + l15;
                s8v bv = *(const s8v*)(&smem[ftb + f * 64 + (((quad + f) & 3) << 4)]);
                #pragma unroll
                for (int mt = 0; mt < 2; ++mt) {
                    f4v acc = {0,0,0,0};
                    acc = MFMA(aa[mt], bv, acc);
                    #pragma unroll
                    for (int r = 0; r < 4; ++r) {
                        int t = quad * 4 + r + 16 * mt;
                        out[((size_t)(t * S_ + s)) * F_ + f] = acc[r];
                    }
                }
            }
        }
        // no barrier needed here: next iter's LDS writes are all ≥2 barriers away
    }
}

extern "C" void kernel_launch(void* const* d_in, const int* in_sizes, int n_in,
                              void* d_out, int out_size, void* d_ws, size_t ws_size,
                              hipStream_t stream) {
    (void)in_sizes; (void)n_in; (void)ws_size; (void)out_size;
    const float* X  = (const float*)d_in[0];   // batch_data [T*S, F] f32
    // d_in[1] = xywh (dead path)
    const float* Wa = (const float*)d_in[2];
    const float* ba = (const float*)d_in[3];
    const float* Wb = (const float*)d_in[4];
    const float* bb = (const float*)d_in[5];
    const float* Wg = (const float*)d_in[6];
    const float* bg = (const float*)d_in[7];
    // d_in[8] = Wh, d_in[9] = bh (dead path)
    float* out = (float*)d_out;
    unsigned short* wsB = (unsigned short*)d_ws;   // 192 KB bf16 weights

    convert_weights<<<dim3(96), dim3(256), 0, stream>>>(Wa, Wb, Wg, wsB);
    fused_temporal<<<dim3(NBLK), dim3(256), 0, stream>>>(X, wsB, ba, bb, bg, out);
}